// Round 1
// baseline (221.379 us; speedup 1.0000x reference)
//
#include <hip/hip_runtime.h>

#define RES   64
#define RES2  (RES*RES)        // 4096
#define RES3  (RES*RES*RES)    // 262144
#define NB    2
#define CIN   16
#define COUT  32
#define NVOX  (NB*RES3)        // 524288
#define NW    (27*CIN*COUT)    // 13824

// ws layout:
//   [0..15]                      : unsigned int counter (16B aligned pad)
//   [16 .. 16+NVOX*4)            : int list[NVOX]
//   [16+NVOX*4 .. +NW*4)         : float w_t[27][CIN][COUT]
// total ≈ 2.15 MiB

// Kernel 1: weight transpose  w[1][o][ci][kd][kh][kw] -> w_t[tap][ci][o]
// Also zero the compaction counter (runs before compact on the same stream).
__global__ __launch_bounds__(256) void wtrans_kernel(
    const float* __restrict__ w, float* __restrict__ wt,
    unsigned int* __restrict__ counter) {
    if (blockIdx.x == 0 && threadIdx.x == 0) *counter = 0u;
    int i = blockIdx.x * 256 + threadIdx.x;
    if (i >= NW) return;
    int tap = i / (CIN * COUT);
    int r   = i % (CIN * COUT);
    int ci  = r / COUT;
    int o   = r % COUT;
    // original: w[(o*CIN + ci)*27 + tap]
    wt[i] = w[(o * CIN + ci) * 27 + tap];
}

// Kernel 2: occupancy + order-preserving block compaction.
// Inactive voxels: write the 32 output zeros here (covers the 0xAA poison).
__global__ __launch_bounds__(256) void compact_kernel(
    const float* __restrict__ x, float* __restrict__ out,
    int* __restrict__ list, unsigned int* __restrict__ counter) {
    int v  = blockIdx.x * 256 + threadIdx.x;   // grid exactly covers NVOX
    int b  = v >> 18;                          // /RES3
    int sp = v & (RES3 - 1);
    bool act = false;
    #pragma unroll
    for (int ci = 0; ci < CIN; ++ci) {
        float val = x[(b * CIN + ci) * RES3 + sp];
        act = act || (val != 0.0f);
    }
    unsigned long long m = __ballot(act);
    int lane = threadIdx.x & 63;
    int wid  = threadIdx.x >> 6;
    __shared__ int wcnt[4];
    __shared__ int wbase[4];
    if (lane == 0) wcnt[wid] = __popcll(m);
    __syncthreads();
    if (threadIdx.x == 0) {
        int c0 = wcnt[0], c1 = wcnt[1], c2 = wcnt[2], c3 = wcnt[3];
        int base = (int)atomicAdd(counter, (unsigned)(c0 + c1 + c2 + c3));
        wbase[0] = base;
        wbase[1] = base + c0;
        wbase[2] = base + c0 + c1;
        wbase[3] = base + c0 + c1 + c2;
    }
    __syncthreads();
    if (act) {
        int pos = wbase[wid] + __popcll(m & ((1ull << lane) - 1ull));
        list[pos] = v;
    } else {
        float* ob = out + (size_t)b * COUT * RES3 + sp;
        #pragma unroll
        for (int o = 0; o < COUT; ++o) ob[o * RES3] = 0.0f;
    }
}

// Kernel 3: direct conv at active voxels only.
// Per thread: 1 voxel, 32 fp32 accumulators, weights via wave-uniform
// (scalar) loads from w_t[tap][ci][o].
__global__ __launch_bounds__(256) void sconv_kernel(
    const float* __restrict__ x, const float* __restrict__ wt,
    const int* __restrict__ list, const unsigned int* __restrict__ counter,
    float* __restrict__ out) {
    unsigned int n = *counter;
    unsigned int i = blockIdx.x * 256 + threadIdx.x;
    if (i >= n) return;
    int v  = list[i];
    int b  = v >> 18;
    int sp = v & (RES3 - 1);
    int z  = sp >> 12;
    int y  = (sp >> 6) & 63;
    int xw = sp & 63;

    float acc[COUT];
    #pragma unroll
    for (int o = 0; o < COUT; ++o) acc[o] = 0.0f;

    const float* xb = x + (size_t)b * CIN * RES3;
    const bool lok = (xw > 0), rok = (xw < RES - 1);

    #pragma unroll
    for (int dz = -1; dz <= 1; ++dz) {
        int nz = z + dz;
        if ((unsigned)nz >= RES) continue;
        #pragma unroll
        for (int dy = -1; dy <= 1; ++dy) {
            int ny = y + dy;
            if ((unsigned)ny >= RES) continue;
            int tap9  = ((dz + 1) * 9 + (dy + 1) * 3) * (CIN * COUT); // +dxidx*512
            int sbase = nz * RES2 + ny * RES + xw;
            for (int ci = 0; ci < CIN; ++ci) {
                const float* xp = xb + ci * RES3 + sbase;
                float x0 = 0.0f, x2 = 0.0f;
                if (lok) x0 = xp[-1];
                float x1 = xp[0];
                if (rok) x2 = xp[1];
                const float* wp = wt + tap9 + ci * COUT;
                #pragma unroll
                for (int o = 0; o < COUT; ++o) {
                    float a = acc[o];
                    a += x0 * wp[o];                    // dx = -1
                    a += x1 * wp[CIN * COUT + o];       // dx =  0
                    a += x2 * wp[2 * CIN * COUT + o];   // dx = +1
                    acc[o] = a;
                }
            }
        }
    }
    float* ob = out + (size_t)b * COUT * RES3 + sp;
    #pragma unroll
    for (int o = 0; o < COUT; ++o) ob[o * RES3] = acc[o];
}

extern "C" void kernel_launch(void* const* d_in, const int* in_sizes, int n_in,
                              void* d_out, int out_size, void* d_ws, size_t ws_size,
                              hipStream_t stream) {
    const float* x = (const float*)d_in[0];   // [2,16,64,64,64]
    const float* w = (const float*)d_in[1];   // [1,32,16,3,3,3]
    float* out = (float*)d_out;               // [2,32,64,64,64]

    unsigned int* counter = (unsigned int*)d_ws;
    int*   list = (int*)((char*)d_ws + 16);
    float* wt   = (float*)((char*)d_ws + 16 + (size_t)NVOX * 4);

    // 1) transpose weights + zero counter
    wtrans_kernel<<<(NW + 255) / 256, 256, 0, stream>>>(w, wt, counter);
    // 2) compact active voxels; zero-fill inactive outputs
    compact_kernel<<<NVOX / 256, 256, 0, stream>>>(x, out, list, counter);
    // 3) conv on active voxels only
    sconv_kernel<<<NVOX / 256, 256, 0, stream>>>(x, wt, list, counter, out);
}